// Round 1
// baseline (304.311 us; speedup 1.0000x reference)
//
#include <hip/hip_runtime.h>

#define BB 64
#define NNODE 512
#define FDIM 64

__device__ __forceinline__ float fast_tanh(float x){
    float e = __expf(2.0f * x);
    return 1.0f - 2.0f * __builtin_amdgcn_rcpf(e + 1.0f);
}

// colsum[d] = sum_i a[i][d]
__global__ void k_colsum(const float* __restrict__ a, float* __restrict__ colsum){
    int d = threadIdx.x;
    float s = 0.f;
    #pragma unroll
    for (int i = 0; i < FDIM; i++) s += a[i * FDIM + d];
    colsum[d] = s;
}

// XW[row,d] = sum_c X[row,c] * W[c,d]   (rows flattened over B*NNODE)
__global__ __launch_bounds__(256) void k_xw(const float* __restrict__ X,
                                            const float* __restrict__ W,
                                            float* __restrict__ XW){
    __shared__ float Wl[FDIM][FDIM];
    __shared__ float Xl[4][FDIM];
    int t = threadIdx.x;
    long row0 = (long)blockIdx.x * 4;
    #pragma unroll
    for (int m = 0; m < 16; m++){ int e = t + 256*m; Wl[e >> 6][e & 63] = W[e]; }
    { int r = t >> 6, c = t & 63; Xl[r][c] = X[(row0 + r) * FDIM + c]; }
    __syncthreads();
    int r = t >> 6, d = t & 63;
    float acc = 0.f;
    #pragma unroll
    for (int c4 = 0; c4 < 16; c4++){
        float4 xv = *(const float4*)&Xl[r][c4 * 4];
        acc += xv.x * Wl[c4*4 + 0][d];
        acc += xv.y * Wl[c4*4 + 1][d];
        acc += xv.z * Wl[c4*4 + 2][d];
        acc += xv.w * Wl[c4*4 + 3][d];
    }
    XW[(row0 + r) * FDIM + d] = acc;
}

// M[b,i,f] = sum_k A_[b,i,k] * S[b,k,f],  S[k,f] = XW[k,f]*colsum[f]
// rowsum[b,i] = sum_k A_[b,i,k]
// A_ = A + diag(i < N[b])
__global__ __launch_bounds__(256) void k_m(const float* __restrict__ A,
                                           const float* __restrict__ XW,
                                           const float* __restrict__ colsum,
                                           const int* __restrict__ Ni,
                                           float* __restrict__ M,
                                           float* __restrict__ rowsum){
    __shared__ float Sl[64][64];     // S chunk [k][f]
    __shared__ float Al[16][65];     // A tile  [i][k], padded
    __shared__ float csl[64];
    int t = threadIdx.x;
    int b = blockIdx.y;
    int i0 = blockIdx.x * 16;
    if (t < 64) csl[t] = colsum[t];
    int fq = t & 15, iq = t >> 4;    // thread -> (row iq, f-quad fq)
    int i = i0 + iq;
    float4 acc = make_float4(0.f, 0.f, 0.f, 0.f);
    float rs = 0.f;
    const float* Ab  = A  + ((long)b * NNODE + i0) * NNODE;
    const float* XWb = XW + (long)b * NNODE * FDIM;
    for (int c = 0; c < 8; c++){
        int k0 = c * 64;
        __syncthreads();
        #pragma unroll
        for (int m = 0; m < 4; m++){
            int e = t + 256*m;
            Al[e >> 6][e & 63] = Ab[(long)(e >> 6) * NNODE + k0 + (e & 63)];
        }
        #pragma unroll
        for (int m = 0; m < 16; m++){
            int e = t + 256*m;
            Sl[e >> 6][e & 63] = XWb[(long)(k0 + (e >> 6)) * FDIM + (e & 63)] * csl[e & 63];
        }
        __syncthreads();
        #pragma unroll
        for (int kk = 0; kk < 64; kk++){
            float av = Al[iq][kk];
            float4 s = *(const float4*)&Sl[kk][fq * 4];
            acc.x += av * s.x; acc.y += av * s.y;
            acc.z += av * s.z; acc.w += av * s.w;
            rs += av;
        }
    }
    // N may be int64 (reference) or int32 (harness); N>=1 so int32 N[1]!=0.
    int Nb = (Ni[1] == 0) ? Ni[2 * b] : Ni[b];
    if (i < Nb){
        float4 xv = *(const float4*)&XWb[(long)i * FDIM + fq * 4];
        acc.x += xv.x * csl[fq*4 + 0];
        acc.y += xv.y * csl[fq*4 + 1];
        acc.z += xv.z * csl[fq*4 + 2];
        acc.w += xv.w * csl[fq*4 + 3];
        rs += 1.f;
    }
    *(float4*)&M[((long)b * NNODE + i) * FDIM + fq * 4] = acc;
    if (fq == 0) rowsum[(long)b * NNODE + i] = rs;
}

// H[b,i,d] = sum_j tanh( sum_f M[i,f]*XW[j,f] + rowsum[i]*bias_a[j] ) * XW[j,d] + bias_W[d]
__global__ __launch_bounds__(256) void k_att(const float* __restrict__ M,
                                             const float* __restrict__ rowsum,
                                             const float* __restrict__ XW,
                                             const float* __restrict__ bias_a,
                                             const float* __restrict__ bias_W,
                                             float* __restrict__ H){
    __shared__ float XWl[64][68];   // padded: rows 272B -> 16B aligned, conflict-free b128
    __shared__ float Ml[16][64];
    __shared__ float attl[16][64];
    __shared__ float btile[64];
    __shared__ float rsl[16];
    int t = threadIdx.x;
    int b = blockIdx.y;
    int i0 = blockIdx.x * 16;
    const float* Mb  = M  + ((long)b * NNODE + i0) * FDIM;
    const float* XWb = XW + (long)b * NNODE * FDIM;
    #pragma unroll
    for (int m = 0; m < 4; m++){ int e = t + 256*m; Ml[e >> 6][e & 63] = Mb[e]; }
    if (t < 16) rsl[t] = rowsum[(long)b * NNODE + i0 + t];
    int lane = t & 63, iq = t >> 6;
    float h[4] = {0.f, 0.f, 0.f, 0.f};
    for (int jt = 0; jt < 8; jt++){
        int j0 = jt * 64;
        __syncthreads();   // protect XWl/attl from previous iter reads (also covers Ml/rsl on jt==0)
        #pragma unroll
        for (int m = 0; m < 16; m++){
            int e = t + 256*m;
            XWl[e >> 6][e & 63] = XWb[(long)(j0 + (e >> 6)) * FDIM + (e & 63)];
        }
        if (t < 64) btile[t] = bias_a[j0 + t];
        __syncthreads();
        // phase 1: att tile [16 rows][64 j], thread = (j=lane, rows iq*4..iq*4+3)
        float arg[4];
        #pragma unroll
        for (int r = 0; r < 4; r++) arg[r] = rsl[iq*4 + r] * btile[lane];
        #pragma unroll
        for (int f4 = 0; f4 < 16; f4++){
            float4 w = *(const float4*)&XWl[lane][f4 * 4];
            #pragma unroll
            for (int r = 0; r < 4; r++){
                float4 mv = *(const float4*)&Ml[iq*4 + r][f4 * 4];
                arg[r] += mv.x * w.x + mv.y * w.y + mv.z * w.z + mv.w * w.w;
            }
        }
        #pragma unroll
        for (int r = 0; r < 4; r++) attl[iq*4 + r][lane] = fast_tanh(arg[r]);
        __syncthreads();
        // phase 2: H[i,d] += att[i,jj] * XW[jj,d], thread = (d=lane, rows iq*4..)
        #pragma unroll
        for (int q = 0; q < 16; q++){
            float w0 = XWl[q*4 + 0][lane];
            float w1 = XWl[q*4 + 1][lane];
            float w2 = XWl[q*4 + 2][lane];
            float w3 = XWl[q*4 + 3][lane];
            #pragma unroll
            for (int r = 0; r < 4; r++){
                float4 av = *(const float4*)&attl[iq*4 + r][q * 4];
                h[r] += av.x * w0 + av.y * w1 + av.z * w2 + av.w * w3;
            }
        }
    }
    float bw = bias_W[lane];
    #pragma unroll
    for (int r = 0; r < 4; r++)
        H[((long)b * NNODE + i0 + iq*4 + r) * FDIM + lane] = h[r] + bw;
}

extern "C" void kernel_launch(void* const* d_in, const int* in_sizes, int n_in,
                              void* d_out, int out_size, void* d_ws, size_t ws_size,
                              hipStream_t stream){
    const float* X      = (const float*)d_in[0];
    const float* A      = (const float*)d_in[1];
    const int*   N      = (const int*)  d_in[2];
    const float* W      = (const float*)d_in[3];
    const float* a      = (const float*)d_in[4];
    const float* bias_W = (const float*)d_in[5];
    const float* bias_a = (const float*)d_in[6];
    float* H  = (float*)d_out;
    float* ws = (float*)d_ws;

    float* XW     = ws;                 // 64*512*64 = 2,097,152 floats
    float* M      = ws + 2097152;       // 2,097,152 floats
    float* rowsum = ws + 4194304;       // 32,768 floats
    float* colsum = ws + 4227072;       // 64 floats  (total ~16.9 MB)

    k_colsum<<<1, 64, 0, stream>>>(a, colsum);
    k_xw   <<<BB * NNODE / 4, 256, 0, stream>>>(X, W, XW);
    k_m    <<<dim3(NNODE / 16, BB), 256, 0, stream>>>(A, XW, colsum, N, M, rowsum);
    k_att  <<<dim3(NNODE / 16, BB), 256, 0, stream>>>(M, rowsum, XW, bias_a, bias_W, H);
}

// Round 2
// 147.058 us; speedup vs baseline: 2.0693x; 2.0693x over previous
//
#include <hip/hip_runtime.h>

#define BB 64
#define NN 512
#define FD 64

typedef short bf16x8 __attribute__((ext_vector_type(8)));
typedef float f32x4 __attribute__((ext_vector_type(4)));

__device__ __forceinline__ unsigned short f2bf(float f){
    unsigned u = __builtin_bit_cast(unsigned, f);
    u += 0x7fffu + ((u >> 16) & 1u);           // RNE
    return (unsigned short)(u >> 16);
}
__device__ __forceinline__ float bf2f(unsigned short h){
    unsigned u = ((unsigned)h) << 16;
    return __builtin_bit_cast(float, u);
}
__device__ __forceinline__ float fast_tanh(float x){
    float e = __expf(2.0f * x);                 // overflow -> inf -> tanh=1; underflow -> 0 -> tanh=-1
    return 1.0f - 2.0f * __builtin_amdgcn_rcpf(e + 1.0f);
}

// colsum[d] = sum_i a[i][d];  Wt[d][c] = bf16(W[c][d])
__global__ __launch_bounds__(256) void k_prep(const float* __restrict__ W,
                                              const float* __restrict__ a,
                                              float* __restrict__ colsum,
                                              unsigned short* __restrict__ Wt){
    int t = threadIdx.x;
    if (t < 64){
        float s = 0.f;
        #pragma unroll
        for (int i = 0; i < 64; i++) s += a[i*64 + t];
        colsum[t] = s;
    }
    int e0 = t * 16;
    int d = e0 >> 6, c0 = e0 & 63;
    #pragma unroll
    for (int q = 0; q < 16; q++)
        Wt[e0 + q] = f2bf(W[(c0 + q)*64 + d]);
}

// XW = X @ W via MFMA; emits XWh[b][n][f], XWt[b][f][n], St[b][f][n]=XWt*colsum (all bf16)
__global__ __launch_bounds__(256) void k_xw(const float* __restrict__ X,
                                            const unsigned short* __restrict__ Wt,
                                            const float* __restrict__ colsum,
                                            unsigned short* __restrict__ XWh,
                                            unsigned short* __restrict__ XWt,
                                            unsigned short* __restrict__ St){
    __shared__ unsigned short Xl[64][72];   // +16B pad: 2-way LDS aliasing only (free)
    __shared__ unsigned short Wtl[64][72];
    __shared__ unsigned short Cl[64][72];
    __shared__ float csl[64];
    int t = threadIdx.x;
    int row0 = blockIdx.x * 64;             // flat node row base (= b*512 + n0)
    int r = t >> 2, c0 = (t & 3) * 16;
    {
        const float4* src = (const float4*)&X[(row0 + r)*FD + c0];
        #pragma unroll
        for (int q = 0; q < 4; q++){
            float4 v = src[q];
            ushort4 h; h.x=f2bf(v.x); h.y=f2bf(v.y); h.z=f2bf(v.z); h.w=f2bf(v.w);
            *(ushort4*)&Xl[r][c0 + q*4] = h;
        }
    }
    {
        const uint4* src = (const uint4*)&Wt[r*64 + c0];
        *(uint4*)&Wtl[r][c0]     = src[0];
        *(uint4*)&Wtl[r][c0 + 8] = src[1];
    }
    if (t < 64) csl[t] = colsum[t];
    __syncthreads();

    int lane = t & 63, w = t >> 6, l15 = lane & 15, quad = lane >> 4;
    f32x4 acc[4] = {{0,0,0,0},{0,0,0,0},{0,0,0,0},{0,0,0,0}};
    #pragma unroll
    for (int ks = 0; ks < 2; ks++){
        bf16x8 af = *(const bf16x8*)&Xl[w*16 + l15][ks*32 + quad*8];
        #pragma unroll
        for (int nt = 0; nt < 4; nt++){
            bf16x8 bfr = *(const bf16x8*)&Wtl[nt*16 + l15][ks*32 + quad*8];
            acc[nt] = __builtin_amdgcn_mfma_f32_16x16x32_bf16(af, bfr, acc[nt], 0, 0, 0);
        }
    }
    #pragma unroll
    for (int nt = 0; nt < 4; nt++)
        #pragma unroll
        for (int rg = 0; rg < 4; rg++)
            Cl[w*16 + quad*4 + rg][nt*16 + l15] = f2bf(acc[nt][rg]);
    __syncthreads();
    {   // natural layout out
        uint4 v0 = *(const uint4*)&Cl[r][c0];
        uint4 v1 = *(const uint4*)&Cl[r][c0 + 8];
        *(uint4*)&XWh[(row0 + r)*FD + c0]     = v0;
        *(uint4*)&XWh[(row0 + r)*FD + c0 + 8] = v1;
    }
    {   // transposed + scaled out
        int b = blockIdx.x >> 3;
        int n0 = (blockIdx.x & 7) * 64;
        int f = r;
        float cs = csl[f];
        ushort4 hv[4], sv[4];
        #pragma unroll
        for (int q = 0; q < 4; q++)
            #pragma unroll
            for (int jj = 0; jj < 4; jj++){
                unsigned short hb = Cl[c0 + q*4 + jj][f];
                ((unsigned short*)&hv[q])[jj] = hb;
                ((unsigned short*)&sv[q])[jj] = f2bf(bf2f(hb) * cs);
            }
        unsigned short* dstT = &XWt[(b*64 + f)*NN + n0 + c0];
        unsigned short* dstS = &St [(b*64 + f)*NN + n0 + c0];
        #pragma unroll
        for (int q = 0; q < 4; q++){
            *(ushort4*)&dstT[q*4] = hv[q];
            *(ushort4*)&dstS[q*4] = sv[q];
        }
    }
}

// M = A_ @ S (MFMA, A fp32->bf16 on the fly); rowsum = A_ @ 1 (computed during staging)
__global__ __launch_bounds__(256) void k_m(const float* __restrict__ A,
                                           const unsigned short* __restrict__ St,
                                           const int* __restrict__ Ni,
                                           unsigned short* __restrict__ Mh,
                                           float* __restrict__ rowsum){
    __shared__ unsigned short Al[64][72];
    __shared__ unsigned short Sl[64][72];   // S^T chunk: [f][k_local]
    __shared__ float rsl[64][4];
    int t = threadIdx.x;
    int b = blockIdx.y, it = blockIdx.x;
    int i0 = it * 64;
    int Nb = (Ni[1] == 0) ? Ni[2*b] : Ni[b];   // int64 vs int32 layout
    int r = t >> 2, c0 = (t & 3) * 16;
    int lane = t & 63, w = t >> 6, l15 = lane & 15, quad = lane >> 4;
    f32x4 acc[4] = {{0,0,0,0},{0,0,0,0},{0,0,0,0},{0,0,0,0}};
    float rs = 0.f;
    const float* Ab = A + (b*NN + i0)*NN;
    for (int c = 0; c < 8; c++){
        __syncthreads();
        const float4* src = (const float4*)&Ab[r*NN + c*64 + c0];
        #pragma unroll
        for (int q = 0; q < 4; q++){
            float4 v = src[q];
            rs += v.x + v.y + v.z + v.w;
            ushort4 h; h.x=f2bf(v.x); h.y=f2bf(v.y); h.z=f2bf(v.z); h.w=f2bf(v.w);
            *(ushort4*)&Al[r][c0 + q*4] = h;
        }
        const uint4* s2 = (const uint4*)&St[(b*64 + r)*NN + c*64 + c0];
        *(uint4*)&Sl[r][c0]     = s2[0];
        *(uint4*)&Sl[r][c0 + 8] = s2[1];
        __syncthreads();
        #pragma unroll
        for (int ks = 0; ks < 2; ks++){
            bf16x8 af = *(const bf16x8*)&Al[w*16 + l15][ks*32 + quad*8];
            #pragma unroll
            for (int nt = 0; nt < 4; nt++){
                bf16x8 bfr = *(const bf16x8*)&Sl[nt*16 + l15][ks*32 + quad*8];
                acc[nt] = __builtin_amdgcn_mfma_f32_16x16x32_bf16(af, bfr, acc[nt], 0, 0, 0);
            }
        }
        if (c == it){   // diagonal of A_: M[i,:] += S[i,:] for i < Nb (k==i lands in this chunk)
            #pragma unroll
            for (int nt = 0; nt < 4; nt++)
                #pragma unroll
                for (int rg = 0; rg < 4; rg++){
                    int iloc = w*16 + quad*4 + rg;
                    if (i0 + iloc < Nb)
                        acc[nt][rg] += bf2f(Sl[nt*16 + l15][iloc]);
                }
        }
    }
    rsl[r][t & 3] = rs;
    __syncthreads();
    #pragma unroll
    for (int nt = 0; nt < 4; nt++)
        #pragma unroll
        for (int rg = 0; rg < 4; rg++)
            Al[w*16 + quad*4 + rg][nt*16 + l15] = f2bf(acc[nt][rg]);  // reuse Al as out-tile
    __syncthreads();
    {
        uint4 v0 = *(const uint4*)&Al[r][c0];
        uint4 v1 = *(const uint4*)&Al[r][c0 + 8];
        *(uint4*)&Mh[(b*NN + i0 + r)*FD + c0]     = v0;
        *(uint4*)&Mh[(b*NN + i0 + r)*FD + c0 + 8] = v1;
    }
    if (t < 64){
        float s = rsl[t][0] + rsl[t][1] + rsl[t][2] + rsl[t][3];
        if (i0 + t < Nb) s += 1.f;
        rowsum[b*NN + i0 + t] = s;
    }
}

// H = tanh(M @ XW^T + rs*bias_a) @ XW + bias_W  (flash-style over j-chunks, both GEMMs MFMA)
__global__ __launch_bounds__(256) void k_att(const unsigned short* __restrict__ Mh,
                                             const float* __restrict__ rowsum,
                                             const unsigned short* __restrict__ XWh,
                                             const unsigned short* __restrict__ XWt,
                                             const float* __restrict__ bias_a,
                                             const float* __restrict__ bias_W,
                                             float* __restrict__ H){
    __shared__ unsigned short Ml[64][72];
    __shared__ unsigned short Pl[64][72];
    __shared__ unsigned short XWl[64][72];    // [j_local][f]
    __shared__ unsigned short XWtl[64][72];   // [d][j_local]
    __shared__ float rsl[64];
    __shared__ float bl[64];
    int t = threadIdx.x;
    int b = blockIdx.y, it = blockIdx.x;
    int i0 = it * 64;
    int r = t >> 2, c0 = (t & 3) * 16;
    int lane = t & 63, w = t >> 6, l15 = lane & 15, quad = lane >> 4;
    {
        const uint4* src = (const uint4*)&Mh[(b*NN + i0 + r)*FD + c0];
        *(uint4*)&Ml[r][c0]     = src[0];
        *(uint4*)&Ml[r][c0 + 8] = src[1];
    }
    if (t < 64) rsl[t] = rowsum[b*NN + i0 + t];
    __syncthreads();
    bf16x8 maf[2];   // GEMM1 A-frags are chunk-invariant: hoist
    maf[0] = *(const bf16x8*)&Ml[w*16 + l15][quad*8];
    maf[1] = *(const bf16x8*)&Ml[w*16 + l15][32 + quad*8];
    float rs_r[4];
    #pragma unroll
    for (int rg = 0; rg < 4; rg++) rs_r[rg] = rsl[w*16 + quad*4 + rg];
    f32x4 hacc[4] = {{0,0,0,0},{0,0,0,0},{0,0,0,0},{0,0,0,0}};
    for (int jt = 0; jt < 8; jt++){
        __syncthreads();
        const uint4* s1 = (const uint4*)&XWh[(b*NN + jt*64 + r)*FD + c0];
        *(uint4*)&XWl[r][c0]     = s1[0];
        *(uint4*)&XWl[r][c0 + 8] = s1[1];
        const uint4* s2 = (const uint4*)&XWt[(b*64 + r)*NN + jt*64 + c0];
        *(uint4*)&XWtl[r][c0]     = s2[0];
        *(uint4*)&XWtl[r][c0 + 8] = s2[1];
        if (t < 64) bl[t] = bias_a[jt*64 + t];
        __syncthreads();
        #pragma unroll
        for (int nt = 0; nt < 4; nt++){
            float bv = bl[nt*16 + l15];
            f32x4 arg = { rs_r[0]*bv, rs_r[1]*bv, rs_r[2]*bv, rs_r[3]*bv };
            #pragma unroll
            for (int ks = 0; ks < 2; ks++){
                bf16x8 bfr = *(const bf16x8*)&XWl[nt*16 + l15][ks*32 + quad*8];
                arg = __builtin_amdgcn_mfma_f32_16x16x32_bf16(maf[ks], bfr, arg, 0, 0, 0);
            }
            #pragma unroll
            for (int rg = 0; rg < 4; rg++)
                Pl[w*16 + quad*4 + rg][nt*16 + l15] = f2bf(fast_tanh(arg[rg]));
        }
        __syncthreads();
        #pragma unroll
        for (int ks = 0; ks < 2; ks++){
            bf16x8 paf = *(const bf16x8*)&Pl[w*16 + l15][ks*32 + quad*8];
            #pragma unroll
            for (int dt = 0; dt < 4; dt++){
                bf16x8 bfr = *(const bf16x8*)&XWtl[dt*16 + l15][ks*32 + quad*8];
                hacc[dt] = __builtin_amdgcn_mfma_f32_16x16x32_bf16(paf, bfr, hacc[dt], 0, 0, 0);
            }
        }
    }
    #pragma unroll
    for (int dt = 0; dt < 4; dt++){
        float bw = bias_W[dt*16 + l15];
        #pragma unroll
        for (int rg = 0; rg < 4; rg++)
            H[(b*NN + i0 + w*16 + quad*4 + rg)*FD + dt*16 + l15] = hacc[dt][rg] + bw;
    }
}

extern "C" void kernel_launch(void* const* d_in, const int* in_sizes, int n_in,
                              void* d_out, int out_size, void* d_ws, size_t ws_size,
                              hipStream_t stream){
    const float* X      = (const float*)d_in[0];
    const float* A      = (const float*)d_in[1];
    const int*   N      = (const int*)  d_in[2];
    const float* W      = (const float*)d_in[3];
    const float* a      = (const float*)d_in[4];
    const float* bias_W = (const float*)d_in[5];
    const float* bias_a = (const float*)d_in[6];
    float* H = (float*)d_out;
    char* ws = (char*)d_ws;

    unsigned short* XWh = (unsigned short*)(ws);                         // 4 MB
    unsigned short* XWt = (unsigned short*)(ws + (4u<<20));              // 4 MB
    unsigned short* St  = (unsigned short*)(ws + (8u<<20));              // 4 MB
    unsigned short* Mh  = (unsigned short*)(ws + (12u<<20));             // 4 MB
    float*          rowsum = (float*)(ws + (16u<<20));                   // 128 KB
    unsigned short* Wt     = (unsigned short*)(ws + (16u<<20) + 131072); // 8 KB
    float*          colsum = (float*)(ws + (16u<<20) + 139264);          // 256 B

    k_prep<<<1, 256, 0, stream>>>(W, a, colsum, Wt);
    k_xw  <<<BB * NN / 64, 256, 0, stream>>>(X, Wt, colsum, XWh, XWt, St);
    k_m   <<<dim3(8, BB), 256, 0, stream>>>(A, St, N, Mh, rowsum);
    k_att <<<dim3(8, BB), 256, 0, stream>>>(Mh, rowsum, XWh, XWt, bias_a, bias_W, H);
}